// Round 5
// baseline (359.146 us; speedup 1.0000x reference)
//
#include <hip/hip_runtime.h>

// ---------------------------------------------------------------------------
// SimpleBBoxHead on MI355X (gfx950) — round 5 (= round 4 resubmit, cleanup)
// - vision half of layer 1 factorized: [16 x 32768] @ W1_vis, 2-stage
//   partials; per-token gather folded into GEMM-1 epilogue.
// - ONE fused prep kernel: vis partials + grd f32->bf16 + 4 weight
//   transposes (block-range dispatch) -> device stays BW-saturated.
// - GEMMs: bf16 MFMA 64x64 tile, 3-deep LDS ring, counted s_waitcnt
//   vmcnt(4) + raw s_barrier (T4): one stage stays in flight across the
//   barrier instead of the compiler's full vmcnt(0) drain.
// ---------------------------------------------------------------------------

typedef __attribute__((ext_vector_type(8))) short bf16x8;
typedef __attribute__((ext_vector_type(4))) float f32x4;

#define LM_DIM 4096
#define FF     1024
#define VIS_K  32768
#define NB     16
#define NTOK   2048

__device__ __forceinline__ unsigned short f2bf(float f) {
    unsigned int u = __float_as_uint(f);
    u += 0x7fffu + ((u >> 16) & 1u);   // round-to-nearest-even
    return (unsigned short)(u >> 16);
}
__device__ __forceinline__ float bf2f(unsigned short s) {
    return __uint_as_float(((unsigned int)s) << 16);
}

__device__ __forceinline__ void gload_lds16(const void* g, void* lds) {
    __builtin_amdgcn_global_load_lds(
        (const __attribute__((address_space(1))) unsigned int*)g,
        (__attribute__((address_space(3))) unsigned int*)lds,
        16, 0, 0);
}

// ---------------------------------------------------------------------------
// Fused prep kernel, 6400 blocks x (64,4) threads (block-range dispatch):
//   [0,512)      vis partials: pb[ks][b][n] = sum_{kk<64} vis[b][ks*64+kk]*W1[.][n]
//   [512,4608)   grd f32 -> bf16 (8 elems/thread)
//   [4608,5632)  W1_lang transpose+cvt  (4096x1024 -> [n][k] bf16)
//   [5632,5888)  W2 transpose, [5888,6144) W3, [6144,6400) W4
// ---------------------------------------------------------------------------
__global__ __launch_bounds__(256) void prep_fused(
    const float* __restrict__ W1, const float* __restrict__ vis,
    float* __restrict__ pb,
    const float* __restrict__ grd, unsigned short* __restrict__ grdb,
    unsigned short* __restrict__ W1lT,
    const float* __restrict__ W2,  unsigned short* __restrict__ W2T,
    const float* __restrict__ W3,  unsigned short* __restrict__ W3T,
    const float* __restrict__ W4,  unsigned short* __restrict__ W4T)
{
    const int bid = blockIdx.x;
    const int tid = threadIdx.y * 64 + threadIdx.x;   // 0..255

    if (bid < 512) {
        // ---- vision partial: k-slice of 64, 4 columns per thread ----
        const int k0 = bid * 64;
        __shared__ float sv[NB][64];
        for (int idx = tid; idx < NB * 64; idx += 256) {
            int b = idx >> 6, kk = idx & 63;
            sv[b][kk] = vis[(size_t)b * VIS_K + k0 + kk];
        }
        __syncthreads();
        float acc[NB][4];
#pragma unroll
        for (int b = 0; b < NB; ++b)
#pragma unroll
            for (int c = 0; c < 4; ++c) acc[b][c] = 0.f;
        for (int kk = 0; kk < 64; ++kk) {
            const float* wrow = W1 + (size_t)(k0 + kk) * FF;
            float w0 = wrow[tid], w1 = wrow[tid + 256],
                  w2 = wrow[tid + 512], w3 = wrow[tid + 768];
#pragma unroll
            for (int b = 0; b < NB; ++b) {
                float v = sv[b][kk];
                acc[b][0] += v * w0; acc[b][1] += v * w1;
                acc[b][2] += v * w2; acc[b][3] += v * w3;
            }
        }
#pragma unroll
        for (int b = 0; b < NB; ++b)
#pragma unroll
            for (int c = 0; c < 4; ++c)
                pb[((size_t)bid * NB + b) * FF + tid + c * 256] = acc[b][c];
        return;
    }
    if (bid < 4608) {
        // ---- grd f32 -> bf16 ----
        int i = (bid - 512) * 256 + tid;
        const float4* p = (const float4*)grd + (size_t)i * 2;
        float4 a = p[0], bv = p[1];
        union { unsigned short us[8]; uint4 v; } o;
        o.us[0] = f2bf(a.x);  o.us[1] = f2bf(a.y);
        o.us[2] = f2bf(a.z);  o.us[3] = f2bf(a.w);
        o.us[4] = f2bf(bv.x); o.us[5] = f2bf(bv.y);
        o.us[6] = f2bf(bv.z); o.us[7] = f2bf(bv.w);
        ((uint4*)grdb)[i] = o.v;
        return;
    }
    // ---- transposes: dst[n][k] bf16 = src[k][n] f32, 64x64 tiles ----
    const float* W1l = W1 + (size_t)VIS_K * FF;       // language half of W1
    const float* src; unsigned short* dst; int K, tt;
    if (bid < 5632)      { src = W1l; dst = W1lT; K = LM_DIM; tt = bid - 4608; }
    else if (bid < 5888) { src = W2;  dst = W2T;  K = FF;     tt = bid - 5632; }
    else if (bid < 6144) { src = W3;  dst = W3T;  K = FF;     tt = bid - 5888; }
    else                 { src = W4;  dst = W4T;  K = FF;     tt = bid - 6144; }
    __shared__ float t[64][65];
    const int tilesx = K / 64;
    const int k0 = (tt % tilesx) * 64, n0 = (tt / tilesx) * 64;
    const int tx = threadIdx.x, ty = threadIdx.y;
    for (int r = ty; r < 64; r += 4)
        t[r][tx] = src[(size_t)(k0 + r) * FF + n0 + tx];
    __syncthreads();
    for (int r = ty; r < 64; r += 4)
        dst[(size_t)(n0 + r) * K + k0 + tx] = f2bf(t[tx][r]);
}

// ---------------------------------------------------------------------------
// Stage 2: Vc[b][n] = sum_{ks<512} pb[ks][b][n].  65536 threads; each sums
// 128 slices, 4-contender atomicAdd (Vc pre-zeroed via hipMemsetAsync).
// ---------------------------------------------------------------------------
__global__ __launch_bounds__(256) void vis_reduce(
    const float* __restrict__ pb, float* __restrict__ vc)
{
    const int lin = blockIdx.x * 256 + threadIdx.x;   // 0..65535
    const int n = lin & 1023;
    const int r = lin >> 10;                          // 0..63
    const int b = r >> 2;
    const int q = r & 3;
    float s = 0.f;
#pragma unroll 4
    for (int i = 0; i < 128; ++i) {
        int ks = q * 128 + i;
        s += pb[((size_t)ks * NB + b) * FF + n];
    }
    atomicAdd(&vc[b * FF + n], s);
}

// ---------------------------------------------------------------------------
// bf16 MFMA GEMM:  H[M][N] = relu(A[M][K] @ BT[N][K]^T + bias [+ Vc gather])
// 64x64 tile, BK=64, 4 waves (2x2, 32x32 each).
// 3-deep LDS ring: stage(t+2) issued before compute(t); s_waitcnt vmcnt(4)
// (NOT 0) + raw s_barrier per iter -> one stage stays in flight across the
// barrier (T4).  Ring safety: slot (t+2)%3's last reader is compute(t-1),
// separated by iter-(t-1)'s barrier.
// LDS dest linear (m104), global source pre-swizzled (m173), XOR-swizzled
// ds_read (byte ^= (row&7)<<4).  XCD-aware bijective swizzle (512 % 8 == 0).
// ---------------------------------------------------------------------------
template <int EPI>
__global__ __launch_bounds__(256, 2) void gemm_bt(
    const unsigned short* __restrict__ A,   // [M][K] bf16
    const unsigned short* __restrict__ BT,  // [N][K] bf16
    const float* __restrict__ bias,         // [N]
    const float* __restrict__ Vc,           // [16][N] or null
    const int* __restrict__ tbi,            // [M] or null
    unsigned short* __restrict__ Hout,      // [M][N] bf16
    int M, int N, int K)
{
    __shared__ __align__(16) unsigned char smem[49152];  // 3 x (8KB A + 8KB B)

    const int tid  = threadIdx.x;
    const int lane = tid & 63;
    const int wv   = tid >> 6;
    const int wr   = wv >> 1;
    const int wc   = wv & 1;

    const int nwg  = gridDim.x * gridDim.y;          // 512
    const int bid0 = blockIdx.y * gridDim.x + blockIdx.x;
    const int cpx  = nwg >> 3;
    const int bid  = (bid0 & 7) * cpx + (bid0 >> 3);
    const int bm   = (bid % gridDim.x) * 64;
    const int bn   = (bid / gridDim.x) * 64;

    const int seg  = wv * 2;
    f32x4 acc[2][2];
#pragma unroll
    for (int m = 0; m < 2; ++m)
#pragma unroll
        for (int n = 0; n < 2; ++n) acc[m][n] = (f32x4){0.f, 0.f, 0.f, 0.f};

    auto stage = [&](int slot, int k0) {
        unsigned char* sA = smem + slot * 16384;
        unsigned char* sB = sA + 8192;
#pragma unroll
        for (int c = 0; c < 2; ++c) {
            int sg  = seg + c;
            int off = sg * 1024 + lane * 16;          // linear LDS byte
            int row = off >> 7;                       // 0..63
            int kb  = (off & 127) ^ ((row & 7) << 4); // pre-swizzled source
            gload_lds16((const unsigned char*)A  + ((size_t)(bm + row) * K + k0) * 2 + kb,
                        sA + sg * 1024);
            gload_lds16((const unsigned char*)BT + ((size_t)(bn + row) * K + k0) * 2 + kb,
                        sB + sg * 1024);
        }
    };
    auto compute = [&](int slot) {
        const unsigned char* sA = smem + slot * 16384;
        const unsigned char* sB = sA + 8192;
#pragma unroll
        for (int kk = 0; kk < 2; ++kk) {
            const int kbb = kk * 64 + (lane >> 4) * 16;
            bf16x8 av[2], bv[2];
#pragma unroll
            for (int m = 0; m < 2; ++m) {
                int r = wr * 32 + m * 16 + (lane & 15);
                av[m] = *(const bf16x8*)(sA + r * 128 + (kbb ^ ((r & 7) << 4)));
            }
#pragma unroll
            for (int n = 0; n < 2; ++n) {
                int r = wc * 32 + n * 16 + (lane & 15);
                bv[n] = *(const bf16x8*)(sB + r * 128 + (kbb ^ ((r & 7) << 4)));
            }
#pragma unroll
            for (int m = 0; m < 2; ++m)
#pragma unroll
                for (int n = 0; n < 2; ++n)
                    acc[m][n] = __builtin_amdgcn_mfma_f32_16x16x32_bf16(
                        av[m], bv[n], acc[m][n], 0, 0, 0);
        }
    };

    const int nt = K >> 6;
    stage(0, 0);
    stage(1, 64);
    asm volatile("s_waitcnt vmcnt(4)" ::: "memory");   // slot 0 landed
    __builtin_amdgcn_s_barrier();
    int slot = 0;
    for (int t = 0; t < nt; ++t) {
        if (t + 2 < nt) {
            int s2 = slot + 2; if (s2 >= 3) s2 -= 3;
            stage(s2, (t + 2) << 6);                   // 8 outstanding
            compute(slot);
            asm volatile("s_waitcnt vmcnt(4)" ::: "memory");  // t+1 landed, t+2 in flight
        } else {
            compute(slot);
            asm volatile("s_waitcnt vmcnt(0)" ::: "memory");  // tail drain
        }
        __builtin_amdgcn_s_barrier();
        if (++slot == 3) slot = 0;
    }

    // Epilogue. C/D layout (m89): col = lane&15, row = (lane>>4)*4+j
#pragma unroll
    for (int m = 0; m < 2; ++m) {
#pragma unroll
        for (int j = 0; j < 4; ++j) {
            int grow = bm + wr * 32 + m * 16 + (lane >> 4) * 4 + j;
            const float* vrow = (EPI == 1) ? (Vc + (size_t)tbi[grow] * N) : nullptr;
#pragma unroll
            for (int n = 0; n < 2; ++n) {
                int gcol = bn + wc * 32 + n * 16 + (lane & 15);
                float v = acc[m][n][j] + bias[gcol];
                if (EPI == 1) v += vrow[gcol];
                v = fmaxf(v, 0.f);
                Hout[(size_t)grow * N + gcol] = f2bf(v);
            }
        }
    }
}

// ---------------------------------------------------------------------------
// Final projection: out[t][j] = sum_k h[t][k]*W5[k][j] + b5[j]   (N=6, fp32)
// ---------------------------------------------------------------------------
__global__ __launch_bounds__(256) void final_proj(
    const unsigned short* __restrict__ H, const float* __restrict__ W5,
    const float* __restrict__ b5, float* __restrict__ out)
{
    const int t    = blockIdx.x * 4 + (threadIdx.x >> 6);
    const int lane = threadIdx.x & 63;
    float s[6] = {0.f, 0.f, 0.f, 0.f, 0.f, 0.f};
    const ushort4* hrow = (const ushort4*)(H + (size_t)t * FF);
#pragma unroll
    for (int i = 0; i < 4; ++i) {
        ushort4 hv = hrow[i * 64 + lane];
        int kbase = (i * 64 + lane) * 4;
#pragma unroll
        for (int c = 0; c < 4; ++c) {
            float h = bf2f(c == 0 ? hv.x : c == 1 ? hv.y : c == 2 ? hv.z : hv.w);
#pragma unroll
            for (int j = 0; j < 6; ++j) s[j] += h * W5[(size_t)(kbase + c) * 6 + j];
        }
    }
#pragma unroll
    for (int j = 0; j < 6; ++j) {
#pragma unroll
        for (int off = 32; off > 0; off >>= 1) s[j] += __shfl_down(s[j], off);
    }
    if (lane == 0) {
#pragma unroll
        for (int j = 0; j < 6; ++j) out[(size_t)t * 6 + j] = s[j] + b5[j];
    }
}

// ---------------------------------------------------------------------------
extern "C" void kernel_launch(void* const* d_in, const int* in_sizes, int n_in,
                              void* d_out, int out_size, void* d_ws, size_t ws_size,
                              hipStream_t stream) {
    const float* grd = (const float*)d_in[0];
    const float* vis = (const float*)d_in[1];
    const int*   tbi = (const int*)d_in[2];
    const float* W1  = (const float*)d_in[3];
    const float* b1  = (const float*)d_in[4];
    const float* W2  = (const float*)d_in[5];
    const float* b2  = (const float*)d_in[6];
    const float* W3  = (const float*)d_in[7];
    const float* b3  = (const float*)d_in[8];
    const float* W4  = (const float*)d_in[9];
    const float* b4  = (const float*)d_in[10];
    const float* W5  = (const float*)d_in[11];
    const float* b5  = (const float*)d_in[12];
    float* out = (float*)d_out;

    char* ws = (char*)d_ws;
    float*          pb    = (float*)ws;                           // 32 MB
    float*          Vc    = (float*)(ws + 33554432);              // 64 KB
    unsigned short* grdb  = (unsigned short*)(ws + 33619968);     // 16 MB
    unsigned short* W1lT  = (unsigned short*)(ws + 50397184);     //  8 MB
    unsigned short* W2T   = (unsigned short*)(ws + 58785792);     //  2 MB
    unsigned short* W3T   = (unsigned short*)(ws + 60882944);     //  2 MB
    unsigned short* W4T   = (unsigned short*)(ws + 62980096);     //  2 MB
    unsigned short* hA    = (unsigned short*)(ws + 65077248);     //  4 MB
    unsigned short* hB    = (unsigned short*)(ws + 69271552);     //  4 MB

    hipMemsetAsync(Vc, 0, NB * FF * sizeof(float), stream);
    prep_fused<<<6400, dim3(64, 4), 0, stream>>>(
        W1, vis, pb, grd, grdb, W1lT, W2, W2T, W3, W3T, W4, W4T);
    vis_reduce<<<256, 256, 0, stream>>>(pb, Vc);

    gemm_bt<1><<<dim3(NTOK / 64, FF / 64), 256, 0, stream>>>(
        grdb, W1lT, b1, Vc, tbi, hA, NTOK, FF, LM_DIM);
    gemm_bt<0><<<dim3(NTOK / 64, FF / 64), 256, 0, stream>>>(
        hA, W2T, b2, nullptr, nullptr, hB, NTOK, FF, FF);
    gemm_bt<0><<<dim3(NTOK / 64, FF / 64), 256, 0, stream>>>(
        hB, W3T, b3, nullptr, nullptr, hA, NTOK, FF, FF);
    gemm_bt<0><<<dim3(NTOK / 64, FF / 64), 256, 0, stream>>>(
        hA, W4T, b4, nullptr, nullptr, hB, NTOK, FF, FF);

    final_proj<<<NTOK / 4, 256, 0, stream>>>(hB, W5, b5, out);
}

// Round 7
// 355.894 us; speedup vs baseline: 1.0091x; 1.0091x over previous
//
#include <hip/hip_runtime.h>

// ---------------------------------------------------------------------------
// SimpleBBoxHead on MI355X (gfx950) — round 7 (= round 6 resubmit; broker
// timeout, never measured)
// - vision half of layer 1 factorized: [16 x 32768] @ W1_vis fp32.
//   r5 lesson: fusing the vis contraction with cvt/transposes strangled it
//   (shared LDS/VGPR budget -> 45% occ, spills, 1.7 TB/s). Now a dedicated
//   streaming kernel: 512x512thr, float4 loads, 32-VGPR accumulator.
// - cvt + 4 weight transposes: own kernel (round-3 shape, was <87us).
// - GEMMs: bf16 MFMA 64x64 tile, 3-deep LDS ring, counted vmcnt(4) (T4).
// ---------------------------------------------------------------------------

typedef __attribute__((ext_vector_type(8))) short bf16x8;
typedef __attribute__((ext_vector_type(4))) float f32x4;

#define LM_DIM 4096
#define FF     1024
#define VIS_K  32768
#define NB     16
#define NTOK   2048

__device__ __forceinline__ unsigned short f2bf(float f) {
    unsigned int u = __float_as_uint(f);
    u += 0x7fffu + ((u >> 16) & 1u);   // round-to-nearest-even
    return (unsigned short)(u >> 16);
}
__device__ __forceinline__ float bf2f(unsigned short s) {
    return __uint_as_float(((unsigned int)s) << 16);
}

__device__ __forceinline__ void gload_lds16(const void* g, void* lds) {
    __builtin_amdgcn_global_load_lds(
        (const __attribute__((address_space(1))) unsigned int*)g,
        (__attribute__((address_space(3))) unsigned int*)lds,
        16, 0, 0);
}

// ---------------------------------------------------------------------------
// Vision partials: pb[ks][b][n] = sum_{kk<64} vis[b][ks*64+kk] * W1[ks*64+kk][n]
// 512 blocks (K-slice of 64 each) x 512 threads.
// thread = (half, c4): half=tid>>8 covers b in [half*8, half*8+8),
// c4=tid&255 covers cols [4*c4, 4*c4+4) via float4.
// acc = 8 x float4 = 32 VGPRs (no spill); 1 x 16B load per inner iter;
// 8 waves/block -> plenty of waves to hide ~900cy HBM latency.
// ---------------------------------------------------------------------------
__global__ __launch_bounds__(512) void vis_partial(
    const float* __restrict__ W1, const float* __restrict__ vis,
    float* __restrict__ pb)
{
    const int tid  = threadIdx.x;        // 0..511
    const int half = tid >> 8;           // 0/1
    const int c4   = tid & 255;          // float4 column index
    const int ks   = blockIdx.x;         // 0..511
    const int k0   = ks * 64;

    __shared__ float sv[NB][64];
    for (int idx = tid; idx < NB * 64; idx += 512) {
        int b = idx >> 6, kk = idx & 63;
        sv[b][kk] = vis[(size_t)b * VIS_K + k0 + kk];
    }
    __syncthreads();

    float4 acc[8];
#pragma unroll
    for (int i = 0; i < 8; ++i) acc[i] = (float4){0.f, 0.f, 0.f, 0.f};

    const float4* Wp = (const float4*)W1 + (size_t)k0 * (FF / 4) + c4;
#pragma unroll 4
    for (int kk = 0; kk < 64; ++kk) {
        float4 w = Wp[(size_t)kk * (FF / 4)];
#pragma unroll
        for (int i = 0; i < 8; ++i) {
            float s = sv[half * 8 + i][kk];
            acc[i].x += s * w.x; acc[i].y += s * w.y;
            acc[i].z += s * w.z; acc[i].w += s * w.w;
        }
    }
#pragma unroll
    for (int i = 0; i < 8; ++i) {
        int b = half * 8 + i;
        ((float4*)pb)[((size_t)ks * NB + b) * (FF / 4) + c4] = acc[i];
    }
}

// ---------------------------------------------------------------------------
// Stage 2: Vc[b][n] = sum_{ks<512} pb[ks][b][n].  65536 threads; each sums
// 128 slices, 4-contender atomicAdd (Vc pre-zeroed via hipMemsetAsync).
// ---------------------------------------------------------------------------
__global__ __launch_bounds__(256) void vis_reduce(
    const float* __restrict__ pb, float* __restrict__ vc)
{
    const int lin = blockIdx.x * 256 + threadIdx.x;   // 0..65535
    const int n = lin & 1023;
    const int r = lin >> 10;                          // 0..63
    const int b = r >> 2;
    const int q = r & 3;
    float s = 0.f;
#pragma unroll 4
    for (int i = 0; i < 128; ++i) {
        int ks = q * 128 + i;
        s += pb[((size_t)ks * NB + b) * FF + n];
    }
    atomicAdd(&vc[b * FF + n], s);
}

// ---------------------------------------------------------------------------
// cvt + transposes, 5888 blocks x (64,4):
//   [0,4096)     grd f32 -> bf16 (8 elems/thread)
//   [4096,5120)  W1_lang transpose+cvt (4096x1024 -> [n][k] bf16)
//   [5120,5376)  W2, [5376,5632) W3, [5632,5888) W4
// ---------------------------------------------------------------------------
__global__ __launch_bounds__(256) void prep_cvt(
    const float* __restrict__ grd, unsigned short* __restrict__ grdb,
    const float* __restrict__ W1l, unsigned short* __restrict__ W1lT,
    const float* __restrict__ W2,  unsigned short* __restrict__ W2T,
    const float* __restrict__ W3,  unsigned short* __restrict__ W3T,
    const float* __restrict__ W4,  unsigned short* __restrict__ W4T)
{
    const int bid = blockIdx.x;
    const int tid = threadIdx.y * 64 + threadIdx.x;

    if (bid < 4096) {
        int i = bid * 256 + tid;
        const float4* p = (const float4*)grd + (size_t)i * 2;
        float4 a = p[0], bv = p[1];
        union { unsigned short us[8]; uint4 v; } o;
        o.us[0] = f2bf(a.x);  o.us[1] = f2bf(a.y);
        o.us[2] = f2bf(a.z);  o.us[3] = f2bf(a.w);
        o.us[4] = f2bf(bv.x); o.us[5] = f2bf(bv.y);
        o.us[6] = f2bf(bv.z); o.us[7] = f2bf(bv.w);
        ((uint4*)grdb)[i] = o.v;
        return;
    }
    const float* src; unsigned short* dst; int K, tt;
    if (bid < 5120)      { src = W1l; dst = W1lT; K = LM_DIM; tt = bid - 4096; }
    else if (bid < 5376) { src = W2;  dst = W2T;  K = FF;     tt = bid - 5120; }
    else if (bid < 5632) { src = W3;  dst = W3T;  K = FF;     tt = bid - 5376; }
    else                 { src = W4;  dst = W4T;  K = FF;     tt = bid - 5632; }
    __shared__ float t[64][65];
    const int tilesx = K / 64;
    const int k0 = (tt % tilesx) * 64, n0 = (tt / tilesx) * 64;
    const int tx = threadIdx.x, ty = threadIdx.y;
    for (int r = ty; r < 64; r += 4)
        t[r][tx] = src[(size_t)(k0 + r) * FF + n0 + tx];
    __syncthreads();
    for (int r = ty; r < 64; r += 4)
        dst[(size_t)(n0 + r) * K + k0 + tx] = f2bf(t[tx][r]);
}

// ---------------------------------------------------------------------------
// bf16 MFMA GEMM:  H[M][N] = relu(A[M][K] @ BT[N][K]^T + bias [+ Vc gather])
// 64x64 tile, BK=64, 4 waves (2x2, 32x32 each).
// 3-deep LDS ring, counted s_waitcnt vmcnt(4) + raw s_barrier (T4).
// LDS dest linear (m104), global source pre-swizzled (m173), XOR-swizzled
// ds_read (byte ^= (row&7)<<4).  XCD-aware bijective swizzle (512 % 8 == 0).
// ---------------------------------------------------------------------------
template <int EPI>
__global__ __launch_bounds__(256, 2) void gemm_bt(
    const unsigned short* __restrict__ A,   // [M][K] bf16
    const unsigned short* __restrict__ BT,  // [N][K] bf16
    const float* __restrict__ bias,         // [N]
    const float* __restrict__ Vc,           // [16][N] or null
    const int* __restrict__ tbi,            // [M] or null
    unsigned short* __restrict__ Hout,      // [M][N] bf16
    int M, int N, int K)
{
    __shared__ __align__(16) unsigned char smem[49152];  // 3 x (8KB A + 8KB B)

    const int tid  = threadIdx.x;
    const int lane = tid & 63;
    const int wv   = tid >> 6;
    const int wr   = wv >> 1;
    const int wc   = wv & 1;

    const int nwg  = gridDim.x * gridDim.y;          // 512
    const int bid0 = blockIdx.y * gridDim.x + blockIdx.x;
    const int cpx  = nwg >> 3;
    const int bid  = (bid0 & 7) * cpx + (bid0 >> 3);
    const int bm   = (bid % gridDim.x) * 64;
    const int bn   = (bid / gridDim.x) * 64;

    const int seg  = wv * 2;
    f32x4 acc[2][2];
#pragma unroll
    for (int m = 0; m < 2; ++m)
#pragma unroll
        for (int n = 0; n < 2; ++n) acc[m][n] = (f32x4){0.f, 0.f, 0.f, 0.f};

    auto stage = [&](int slot, int k0) {
        unsigned char* sA = smem + slot * 16384;
        unsigned char* sB = sA + 8192;
#pragma unroll
        for (int c = 0; c < 2; ++c) {
            int sg  = seg + c;
            int off = sg * 1024 + lane * 16;          // linear LDS byte
            int row = off >> 7;                       // 0..63
            int kb  = (off & 127) ^ ((row & 7) << 4); // pre-swizzled source
            gload_lds16((const unsigned char*)A  + ((size_t)(bm + row) * K + k0) * 2 + kb,
                        sA + sg * 1024);
            gload_lds16((const unsigned char*)BT + ((size_t)(bn + row) * K + k0) * 2 + kb,
                        sB + sg * 1024);
        }
    };
    auto compute = [&](int slot) {
        const unsigned char* sA = smem + slot * 16384;
        const unsigned char* sB = sA + 8192;
#pragma unroll
        for (int kk = 0; kk < 2; ++kk) {
            const int kbb = kk * 64 + (lane >> 4) * 16;
            bf16x8 av[2], bv[2];
#pragma unroll
            for (int m = 0; m < 2; ++m) {
                int r = wr * 32 + m * 16 + (lane & 15);
                av[m] = *(const bf16x8*)(sA + r * 128 + (kbb ^ ((r & 7) << 4)));
            }
#pragma unroll
            for (int n = 0; n < 2; ++n) {
                int r = wc * 32 + n * 16 + (lane & 15);
                bv[n] = *(const bf16x8*)(sB + r * 128 + (kbb ^ ((r & 7) << 4)));
            }
#pragma unroll
            for (int m = 0; m < 2; ++m)
#pragma unroll
                for (int n = 0; n < 2; ++n)
                    acc[m][n] = __builtin_amdgcn_mfma_f32_16x16x32_bf16(
                        av[m], bv[n], acc[m][n], 0, 0, 0);
        }
    };

    const int nt = K >> 6;
    stage(0, 0);
    stage(1, 64);
    asm volatile("s_waitcnt vmcnt(4)" ::: "memory");   // slot 0 landed
    __builtin_amdgcn_s_barrier();
    int slot = 0;
    for (int t = 0; t < nt; ++t) {
        if (t + 2 < nt) {
            int s2 = slot + 2; if (s2 >= 3) s2 -= 3;
            stage(s2, (t + 2) << 6);                   // 8 outstanding
            compute(slot);
            asm volatile("s_waitcnt vmcnt(4)" ::: "memory");  // t+1 landed
        } else {
            compute(slot);
            asm volatile("s_waitcnt vmcnt(0)" ::: "memory");  // tail drain
        }
        __builtin_amdgcn_s_barrier();
        if (++slot == 3) slot = 0;
    }

    // Epilogue. C/D layout (m89): col = lane&15, row = (lane>>4)*4+j
#pragma unroll
    for (int m = 0; m < 2; ++m) {
#pragma unroll
        for (int j = 0; j < 4; ++j) {
            int grow = bm + wr * 32 + m * 16 + (lane >> 4) * 4 + j;
            const float* vrow = (EPI == 1) ? (Vc + (size_t)tbi[grow] * N) : nullptr;
#pragma unroll
            for (int n = 0; n < 2; ++n) {
                int gcol = bn + wc * 32 + n * 16 + (lane & 15);
                float v = acc[m][n][j] + bias[gcol];
                if (EPI == 1) v += vrow[gcol];
                v = fmaxf(v, 0.f);
                Hout[(size_t)grow * N + gcol] = f2bf(v);
            }
        }
    }
}

// ---------------------------------------------------------------------------
// Final projection: out[t][j] = sum_k h[t][k]*W5[k][j] + b5[j]   (N=6, fp32)
// ---------------------------------------------------------------------------
__global__ __launch_bounds__(256) void final_proj(
    const unsigned short* __restrict__ H, const float* __restrict__ W5,
    const float* __restrict__ b5, float* __restrict__ out)
{
    const int t    = blockIdx.x * 4 + (threadIdx.x >> 6);
    const int lane = threadIdx.x & 63;
    float s[6] = {0.f, 0.f, 0.f, 0.f, 0.f, 0.f};
    const ushort4* hrow = (const ushort4*)(H + (size_t)t * FF);
#pragma unroll
    for (int i = 0; i < 4; ++i) {
        ushort4 hv = hrow[i * 64 + lane];
        int kbase = (i * 64 + lane) * 4;
#pragma unroll
        for (int c = 0; c < 4; ++c) {
            float h = bf2f(c == 0 ? hv.x : c == 1 ? hv.y : c == 2 ? hv.z : hv.w);
#pragma unroll
            for (int j = 0; j < 6; ++j) s[j] += h * W5[(size_t)(kbase + c) * 6 + j];
        }
    }
#pragma unroll
    for (int j = 0; j < 6; ++j) {
#pragma unroll
        for (int off = 32; off > 0; off >>= 1) s[j] += __shfl_down(s[j], off);
    }
    if (lane == 0) {
#pragma unroll
        for (int j = 0; j < 6; ++j) out[(size_t)t * 6 + j] = s[j] + b5[j];
    }
}

// ---------------------------------------------------------------------------
extern "C" void kernel_launch(void* const* d_in, const int* in_sizes, int n_in,
                              void* d_out, int out_size, void* d_ws, size_t ws_size,
                              hipStream_t stream) {
    const float* grd = (const float*)d_in[0];
    const float* vis = (const float*)d_in[1];
    const int*   tbi = (const int*)d_in[2];
    const float* W1  = (const float*)d_in[3];
    const float* b1  = (const float*)d_in[4];
    const float* W2  = (const float*)d_in[5];
    const float* b2  = (const float*)d_in[6];
    const float* W3  = (const float*)d_in[7];
    const float* b3  = (const float*)d_in[8];
    const float* W4  = (const float*)d_in[9];
    const float* b4  = (const float*)d_in[10];
    const float* W5  = (const float*)d_in[11];
    const float* b5  = (const float*)d_in[12];
    float* out = (float*)d_out;

    char* ws = (char*)d_ws;
    float*          pb    = (float*)ws;                           // 32 MB
    float*          Vc    = (float*)(ws + 33554432);              // 64 KB
    unsigned short* grdb  = (unsigned short*)(ws + 33619968);     // 16 MB
    unsigned short* W1lT  = (unsigned short*)(ws + 50397184);     //  8 MB
    unsigned short* W2T   = (unsigned short*)(ws + 58785792);     //  2 MB
    unsigned short* W3T   = (unsigned short*)(ws + 60882944);     //  2 MB
    unsigned short* W4T   = (unsigned short*)(ws + 62980096);     //  2 MB
    unsigned short* hA    = (unsigned short*)(ws + 65077248);     //  4 MB
    unsigned short* hB    = (unsigned short*)(ws + 69271552);     //  4 MB

    hipMemsetAsync(Vc, 0, NB * FF * sizeof(float), stream);
    vis_partial<<<512, 512, 0, stream>>>(W1, vis, pb);
    prep_cvt<<<5888, dim3(64, 4), 0, stream>>>(
        grd, grdb, W1 + (size_t)VIS_K * FF, W1lT, W2, W2T, W3, W3T, W4, W4T);
    vis_reduce<<<256, 256, 0, stream>>>(pb, Vc);

    gemm_bt<1><<<dim3(NTOK / 64, FF / 64), 256, 0, stream>>>(
        grdb, W1lT, b1, Vc, tbi, hA, NTOK, FF, LM_DIM);
    gemm_bt<0><<<dim3(NTOK / 64, FF / 64), 256, 0, stream>>>(
        hA, W2T, b2, nullptr, nullptr, hB, NTOK, FF, FF);
    gemm_bt<0><<<dim3(NTOK / 64, FF / 64), 256, 0, stream>>>(
        hB, W3T, b3, nullptr, nullptr, hA, NTOK, FF, FF);
    gemm_bt<0><<<dim3(NTOK / 64, FF / 64), 256, 0, stream>>>(
        hA, W4T, b4, nullptr, nullptr, hB, NTOK, FF, FF);

    final_proj<<<NTOK / 4, 256, 0, stream>>>(hB, W5, b5, out);
}